// Round 3
// baseline (490.754 us; speedup 1.0000x reference)
//
#include <hip/hip_runtime.h>

// out[N,32] = segment_sum(edge_val[e] * weight[edge_col[e], :], edge_row[e]) + bias
//
// v3: counting-sort partition into row-buckets + LDS-accumulate.
//   Buckets of RPB=128 rows (B=ceil(N/128) buckets, 782 for N=100000).
//   K0 gnn_zero    : cnt[B] = 0
//   K1 gnn_hist    : per-workgroup LDS histogram of bucket ids over an 8192-edge
//                    chunk, then one global atomicAdd per (wg,bucket). ~150K atomics.
//   K2 gnn_scan    : single-workgroup exclusive scan -> start[B], cursor[B]=start.
//   K3 gnn_part    : re-histogram chunk in LDS, reserve contiguous runs via
//                    atomicAdd(cursor[b], localcount), then write each edge's
//                    packed 8B record (col|rowlow<<17, val) into its run.
//                    Scatter granularity becomes ~10-edge runs instead of 8B
//                    randoms -> write amplification ~1.6x instead of 8x.
//   K4 gnn_accum   : one workgroup per bucket; acc[128][32] f32 in LDS (16KB);
//                    32 lanes per edge gather the weight row (128B coalesced),
//                    LDS atomicAdd (banks 0..31, conflict-free), then one
//                    coalesced out-row store with bias. No out init needed.
//
// Fallbacks: v2 bin+gather if workspace can't hold parts[]; v0 atomics if tiny.

#define FEAT 32
#define LOG_RPB 7
#define RPB (1 << LOG_RPB)          // rows per bucket
#define COLBITS 17                  // col fits 17 bits (N <= 131072)
#define CHUNK 8192                  // edges per partition workgroup
#define BMAX 1024                   // max buckets supported by scan/hist LDS
#define CAP_MAX 32

// ---------------- v3 kernels ----------------

__global__ __launch_bounds__(256) void gnn_zero(int* __restrict__ cnt, int B) {
    int i = blockIdx.x * blockDim.x + threadIdx.x;
    if (i < B) cnt[i] = 0;
}

__global__ __launch_bounds__(256) void gnn_hist(
    const int* __restrict__ edge_row, int* __restrict__ cnt,
    int num_edges, int B) {
    __shared__ int h[BMAX];
    for (int b = threadIdx.x; b < BMAX; b += 256) h[b] = 0;
    __syncthreads();
    int e0 = blockIdx.x * CHUNK;
    #pragma unroll
    for (int k = 0; k < CHUNK / 256; ++k) {
        int e = e0 + k * 256 + threadIdx.x;
        if (e < num_edges) atomicAdd(&h[edge_row[e] >> LOG_RPB], 1);
    }
    __syncthreads();
    for (int b = threadIdx.x; b < B; b += 256) {
        int c = h[b];
        if (c) atomicAdd(&cnt[b], c);
    }
}

__global__ __launch_bounds__(1024) void gnn_scan(
    const int* __restrict__ cnt, int* __restrict__ start,
    int* __restrict__ cursor, int B) {
    __shared__ int s[BMAX];
    int t = threadIdx.x;
    int v = (t < B) ? cnt[t] : 0;
    s[t] = v;
    __syncthreads();
    for (int off = 1; off < BMAX; off <<= 1) {
        int u = (t >= off) ? s[t - off] : 0;
        __syncthreads();
        s[t] += u;
        __syncthreads();
    }
    if (t < B) {
        int st = s[t] - v;   // exclusive
        start[t]  = st;
        cursor[t] = st;
    }
}

__global__ __launch_bounds__(256) void gnn_part(
    const int* __restrict__ edge_row,
    const int* __restrict__ edge_col,
    const float* __restrict__ edge_val,
    int* __restrict__ cursor,
    float2* __restrict__ parts,
    int num_edges, int B) {
    __shared__ int h[BMAX];
    __shared__ int cbase[BMAX];
    for (int b = threadIdx.x; b < BMAX; b += 256) h[b] = 0;
    __syncthreads();
    int e0 = blockIdx.x * CHUNK;
    #pragma unroll
    for (int k = 0; k < CHUNK / 256; ++k) {
        int e = e0 + k * 256 + threadIdx.x;
        if (e < num_edges) atomicAdd(&h[edge_row[e] >> LOG_RPB], 1);
    }
    __syncthreads();
    for (int b = threadIdx.x; b < B; b += 256) {
        int c = h[b];
        cbase[b] = c ? atomicAdd(&cursor[b], c) : 0;
        h[b] = 0;   // reuse as local cursor
    }
    __syncthreads();
    #pragma unroll
    for (int k = 0; k < CHUNK / 256; ++k) {
        int e = e0 + k * 256 + threadIdx.x;
        if (e < num_edges) {
            int r = edge_row[e];
            int b = r >> LOG_RPB;
            int off = atomicAdd(&h[b], 1);
            int pos = cbase[b] + off;
            unsigned pk = (unsigned)edge_col[e] |
                          ((unsigned)(r & (RPB - 1)) << COLBITS);
            parts[pos] = make_float2(__uint_as_float(pk), edge_val[e]);
        }
    }
}

__global__ __launch_bounds__(512) void gnn_accum(
    const float2* __restrict__ parts,
    const int* __restrict__ start,
    const int* __restrict__ cnt,
    const float* __restrict__ weight,
    const float* __restrict__ bias,
    float* __restrict__ out,
    int n_nodes) {
    __shared__ float acc[RPB * FEAT];   // 16 KB
    int b = blockIdx.x;
    for (int i = threadIdx.x; i < RPB * FEAT; i += 512) acc[i] = 0.f;
    __syncthreads();

    int s0 = start[b];
    int n  = cnt[b];
    int g  = threadIdx.x >> 5;          // 16 groups of 32 lanes
    int f  = threadIdx.x & 31;
    const float2* p = parts + s0;
    for (int j = g; j < n; j += 16) {
        float2 rec = p[j];
        unsigned pk = __float_as_uint(rec.x);
        int c  = (int)(pk & ((1u << COLBITS) - 1));
        int rl = (int)(pk >> COLBITS) & (RPB - 1);
        float w = weight[(long long)c * FEAT + f];
        atomicAdd(&acc[rl * FEAT + f], rec.y * w);
    }
    __syncthreads();

    int row0 = b << LOG_RPB;
    for (int i = threadIdx.x; i < RPB * FEAT; i += 512) {
        int r = row0 + (i >> 5);
        if (r < n_nodes)
            out[(long long)r * FEAT + (i & 31)] = acc[i] + bias[i & 31];
    }
}

// ---------------- v2 fallback (bin + gather) ----------------

__global__ __launch_bounds__(256) void gnn_init(
    const float* __restrict__ bias, float* __restrict__ out,
    int* __restrict__ cnt, int total4, int n_nodes) {
    int i = blockIdx.x * blockDim.x + threadIdx.x;
    if (i < total4) {
        float4 bb = ((const float4*)bias)[i & 7];
        ((float4*)out)[i] = bb;
    }
    if (i < n_nodes) cnt[i] = 0;
}

__global__ __launch_bounds__(256) void gnn_bin(
    const int* __restrict__ edge_row,
    const int* __restrict__ edge_col,
    const float* __restrict__ edge_val,
    const float* __restrict__ weight,
    float2* __restrict__ bins,
    int* __restrict__ cnt,
    float* __restrict__ out,
    int num_edges, int cap) {
    int e = blockIdx.x * blockDim.x + threadIdx.x;
    if (e >= num_edges) return;
    int r = edge_row[e];
    int c = edge_col[e];
    float v = edge_val[e];
    int slot = atomicAdd(&cnt[r], 1);
    if (slot < cap) {
        bins[(long long)r * cap + slot] = make_float2(__int_as_float(c), v);
    } else {
        const float* w = weight + (long long)c * FEAT;
        #pragma unroll
        for (int f = 0; f < FEAT; ++f)
            atomicAdd(out + (long long)r * FEAT + f, v * w[f]);
    }
}

__global__ __launch_bounds__(256) void gnn_gather(
    const float2* __restrict__ bins,
    const int* __restrict__ cnt,
    const float* __restrict__ weight,
    float* __restrict__ out,
    int n_nodes, int cap) {
    int g = (blockIdx.x * blockDim.x + threadIdx.x) >> 5;
    int f = threadIdx.x & (FEAT - 1);
    if (g >= n_nodes) return;
    int n = cnt[g];
    n = n < cap ? n : cap;
    const float2* b = bins + (long long)g * cap;
    float acc0 = 0.f, acc1 = 0.f, acc2 = 0.f, acc3 = 0.f;
    int j = 0;
    for (; j + 4 <= n; j += 4) {
        float2 e0 = b[j], e1 = b[j + 1], e2 = b[j + 2], e3 = b[j + 3];
        acc0 += e0.y * weight[(long long)__float_as_int(e0.x) * FEAT + f];
        acc1 += e1.y * weight[(long long)__float_as_int(e1.x) * FEAT + f];
        acc2 += e2.y * weight[(long long)__float_as_int(e2.x) * FEAT + f];
        acc3 += e3.y * weight[(long long)__float_as_int(e3.x) * FEAT + f];
    }
    for (; j < n; ++j) {
        float2 e0 = b[j];
        acc0 += e0.y * weight[(long long)__float_as_int(e0.x) * FEAT + f];
    }
    out[(long long)g * FEAT + f] += (acc0 + acc1) + (acc2 + acc3);
}

// ---------------- v0 fallback ----------------

__global__ __launch_bounds__(256) void gnn_init_out(
    const float* __restrict__ bias, float* __restrict__ out, int total) {
    int i = blockIdx.x * blockDim.x + threadIdx.x;
    if (i < total) out[i] = bias[i & (FEAT - 1)];
}

__global__ __launch_bounds__(256) void gnn_scatter(
    const int* __restrict__ edge_row,
    const int* __restrict__ edge_col,
    const float* __restrict__ edge_val,
    const float* __restrict__ weight,
    float* __restrict__ out,
    int num_edges) {
    long long t = (long long)blockIdx.x * blockDim.x + threadIdx.x;
    int e = (int)(t >> 5);
    int f = (int)(t & (FEAT - 1));
    if (e < num_edges) {
        int r = edge_row[e];
        int c = edge_col[e];
        float v = edge_val[e];
        atomicAdd(out + r * FEAT + f, v * weight[c * FEAT + f]);
    }
}

extern "C" void kernel_launch(void* const* d_in, const int* in_sizes, int n_in,
                              void* d_out, int out_size, void* d_ws, size_t ws_size,
                              hipStream_t stream) {
    const int*   edge_row = (const int*)d_in[0];
    const int*   edge_col = (const int*)d_in[1];
    const float* edge_val = (const float*)d_in[2];
    const float* weight   = (const float*)d_in[3];
    const float* bias     = (const float*)d_in[4];
    float* out = (float*)d_out;

    const int E = in_sizes[0];
    const int total = out_size;        // N * 32 elements
    const int N = total / FEAT;
    const int B = (N + RPB - 1) >> LOG_RPB;

    // v3 workspace layout: cnt[B] | start[B] | cursor[B] | parts[E] float2
    auto align256 = [](size_t x) { return (x + 255) & ~(size_t)255; };
    size_t cnt_off    = 0;
    size_t start_off  = align256(cnt_off + (size_t)B * sizeof(int));
    size_t cursor_off = align256(start_off + (size_t)B * sizeof(int));
    size_t parts_off  = align256(cursor_off + (size_t)B * sizeof(int));
    size_t need_v3    = parts_off + (size_t)E * sizeof(float2);

    if (B <= BMAX && N <= (1 << COLBITS) && ws_size >= need_v3) {
        int* cnt      = (int*)((char*)d_ws + cnt_off);
        int* start    = (int*)((char*)d_ws + start_off);
        int* cursor   = (int*)((char*)d_ws + cursor_off);
        float2* parts = (float2*)((char*)d_ws + parts_off);

        int nwg_part = (E + CHUNK - 1) / CHUNK;
        gnn_zero<<<(B + 255) / 256, 256, 0, stream>>>(cnt, B);
        gnn_hist<<<nwg_part, 256, 0, stream>>>(edge_row, cnt, E, B);
        gnn_scan<<<1, BMAX, 0, stream>>>(cnt, start, cursor, B);
        gnn_part<<<nwg_part, 256, 0, stream>>>(
            edge_row, edge_col, edge_val, cursor, parts, E, B);
        gnn_accum<<<B, 512, 0, stream>>>(
            parts, start, cnt, weight, bias, out, N);
        return;
    }

    // v2 fallback: bin + gather
    size_t cnt_bytes = align256((size_t)N * sizeof(int));
    long long cap_ll = 0;
    if (ws_size > cnt_bytes)
        cap_ll = (long long)((ws_size - cnt_bytes) / ((size_t)N * sizeof(float2)));
    int cap = (int)(cap_ll > CAP_MAX ? CAP_MAX : cap_ll);

    if (cap >= 16) {
        int* cnt = (int*)d_ws;
        float2* bins = (float2*)((char*)d_ws + cnt_bytes);
        int total4 = total / 4;
        int init_threads = total4 > N ? total4 : N;
        gnn_init<<<(init_threads + 255) / 256, 256, 0, stream>>>(
            bias, out, cnt, total4, N);
        gnn_bin<<<(E + 255) / 256, 256, 0, stream>>>(
            edge_row, edge_col, edge_val, weight, bins, cnt, out, E, cap);
        long long gthreads = (long long)N * FEAT;
        gnn_gather<<<(int)((gthreads + 255) / 256), 256, 0, stream>>>(
            bins, cnt, weight, out, N, cap);
    } else {
        gnn_init_out<<<(total + 255) / 256, 256, 0, stream>>>(bias, out, total);
        long long threads = (long long)E * FEAT;
        gnn_scatter<<<(int)((threads + 255) / 256), 256, 0, stream>>>(
            edge_row, edge_col, edge_val, weight, out, E);
    }
}

// Round 4
// 450.679 us; speedup vs baseline: 1.0889x; 1.0889x over previous
//
#include <hip/hip_runtime.h>

// out[N,32] = segment_sum(edge_val[e] * weight[edge_col[e], :], edge_row[e]) + bias
//
// v4: counting-sort into 128-row buckets with LDS-reordered (coalesced) scatter,
// then an 8-way-ILP LDS-accumulate.
//   K0 gnn_zero  : cnt[B] = 0
//   K1 gnn_hist  : per-WG LDS histogram over 8192 edges -> global atomicAdd.
//   K2 gnn_scan  : 1 WG scans 4-record-PADDED counts -> startp[], cursor[]=startp.
//                  (padding makes every bucket start 32B-aligned for float4 reads)
//   K3 gnn_part  : per 4096-edge chunk: LDS hist -> local scan -> reserve global
//                  runs (atomicAdd cursor) -> scatter records into LDS in bucket
//                  order -> linear write-out (consecutive lanes -> consecutive
//                  addresses; ~40B runs, WG-private so lines fill in local L2).
//                  Record = (col | (row&127)<<17, val) packed in 8B.
//   K4 gnn_accum : 1 WG (512 thr) per bucket, acc[128][32] f32 in LDS (16KB).
//                  16 groups x 8 records in flight: float4 bin loads, 8
//                  independent weight-row gathers, 8 ds_add_f32 (bank-conflict
//                  free: lanes 0..31 hit banks 0..31). Coalesced out store +bias.
//
// Fallbacks: v2 bin+gather if ws too small / shape out of range; v0 atomics last.

#define FEAT 32
#define LOG_RPB 7
#define RPB (1 << LOG_RPB)
#define COLBITS 17
#define CMASK ((1u << COLBITS) - 1)
#define BMAX 1024
#define HCHUNK 8192
#define PCHUNK 4096
#define PTHREADS 1024
#define CAP_MAX 32

// ---------------- v4 kernels ----------------

__global__ __launch_bounds__(256) void gnn_zero(int* __restrict__ cnt, int B) {
    int i = blockIdx.x * 256 + threadIdx.x;
    if (i < B) cnt[i] = 0;
}

__global__ __launch_bounds__(256) void gnn_hist(
    const int* __restrict__ edge_row, int* __restrict__ cnt,
    int num_edges, int B) {
    __shared__ int h[BMAX];
    for (int b = threadIdx.x; b < BMAX; b += 256) h[b] = 0;
    __syncthreads();
    int e0 = blockIdx.x * HCHUNK;
    #pragma unroll
    for (int k = 0; k < HCHUNK / 256; ++k) {
        int e = e0 + k * 256 + threadIdx.x;
        if (e < num_edges) atomicAdd(&h[edge_row[e] >> LOG_RPB], 1);
    }
    __syncthreads();
    for (int b = threadIdx.x; b < B; b += 256) {
        int c = h[b];
        if (c) atomicAdd(&cnt[b], c);
    }
}

__global__ __launch_bounds__(1024) void gnn_scan(
    const int* __restrict__ cnt, int* __restrict__ startp,
    int* __restrict__ cursor, int B) {
    __shared__ int s[BMAX];
    int t = threadIdx.x;
    int v  = (t < B) ? cnt[t] : 0;
    int pv = (v + 3) & ~3;              // pad each bucket to a multiple of 4 recs
    s[t] = pv;
    __syncthreads();
    for (int off = 1; off < BMAX; off <<= 1) {
        int u = (t >= off) ? s[t - off] : 0;
        __syncthreads();
        s[t] += u;
        __syncthreads();
    }
    if (t < B) {
        int st = s[t] - pv;             // exclusive scan of padded sizes
        startp[t] = st;
        cursor[t] = st;
    }
}

__global__ __launch_bounds__(PTHREADS) void gnn_part(
    const int* __restrict__ edge_row,
    const int* __restrict__ edge_col,
    const float* __restrict__ edge_val,
    int* __restrict__ cursor,
    float2* __restrict__ parts,
    int num_edges, int B) {
    __shared__ float2 lrec[PCHUNK];     // 32 KB: chunk records in bucket order
    __shared__ int st[BMAX + 1];        // local exclusive starts (raw)
    __shared__ int cur[BMAX];           // hist, then local cursor
    __shared__ int cb[BMAX];            // global base of this WG's run per bucket
    int t = threadIdx.x;
    for (int b = t; b < BMAX; b += PTHREADS) cur[b] = 0;
    __syncthreads();

    int e0 = blockIdx.x * PCHUNK;
    int cnt_chunk = num_edges - e0;
    if (cnt_chunk > PCHUNK) cnt_chunk = PCHUNK;

    // 1) local histogram
    #pragma unroll
    for (int k = 0; k < PCHUNK / PTHREADS; ++k) {
        int e = e0 + k * PTHREADS + t;
        if (e < num_edges) atomicAdd(&cur[edge_row[e] >> LOG_RPB], 1);
    }
    __syncthreads();

    // 2) local exclusive scan + global run reservation
    int v = (t < B) ? cur[t] : 0;
    st[t] = v;
    __syncthreads();
    for (int off = 1; off < BMAX; off <<= 1) {
        int u = (t >= off) ? st[t - off] : 0;
        __syncthreads();
        st[t] += u;
        __syncthreads();
    }
    int incl = st[t];
    __syncthreads();
    if (t < B) {
        int ex = incl - v;
        st[t]  = ex;
        cur[t] = ex;                                    // local cursor
        cb[t]  = v ? atomicAdd(&cursor[t], v) : 0;      // global run base
        if (t == B - 1) st[B] = incl;
    }
    __syncthreads();

    // 3) scatter records into LDS in bucket order
    #pragma unroll
    for (int k = 0; k < PCHUNK / PTHREADS; ++k) {
        int e = e0 + k * PTHREADS + t;
        if (e < num_edges) {
            int r = edge_row[e];
            int b = r >> LOG_RPB;
            int slot = atomicAdd(&cur[b], 1);
            unsigned pk = (unsigned)edge_col[e] |
                          ((unsigned)(r & (RPB - 1)) << COLBITS);
            lrec[slot] = make_float2(__uint_as_float(pk), edge_val[e]);
        }
    }
    __syncthreads();

    // 4) coalesced write-out: LDS slot i -> bucket (binary search) -> global pos
    for (int i = t; i < cnt_chunk; i += PTHREADS) {
        float2 rec = lrec[i];
        int lo = 0, hi = B;
        while (hi - lo > 1) {
            int mid = (lo + hi) >> 1;
            if (st[mid] <= i) lo = mid; else hi = mid;
        }
        parts[(long long)cb[lo] + (i - st[lo])] = rec;
    }
}

__global__ __launch_bounds__(512) void gnn_accum(
    const float2* __restrict__ parts,
    const int* __restrict__ startp,
    const int* __restrict__ cnt,
    const float* __restrict__ weight,
    const float* __restrict__ bias,
    float* __restrict__ out,
    int n_nodes) {
    __shared__ float acc[RPB * FEAT];   // 16 KB
    int b = blockIdx.x;
    for (int i = threadIdx.x; i < RPB * FEAT; i += 512) acc[i] = 0.f;
    __syncthreads();

    int n = cnt[b];
    const float2* p  = parts + startp[b];       // startp multiple of 4 recs
    const float4* p4 = (const float4*)p;        // 16B-aligned
    int g = threadIdx.x >> 5;                   // 16 groups of 32 lanes
    int f = threadIdx.x & 31;

    int j0 = g * 8;
    for (; j0 + 8 <= n; j0 += 128) {
        float4 q0 = p4[(j0 >> 1) + 0];
        float4 q1 = p4[(j0 >> 1) + 1];
        float4 q2 = p4[(j0 >> 1) + 2];
        float4 q3 = p4[(j0 >> 1) + 3];
        unsigned pk[8]; float vv[8];
        pk[0] = __float_as_uint(q0.x); vv[0] = q0.y;
        pk[1] = __float_as_uint(q0.z); vv[1] = q0.w;
        pk[2] = __float_as_uint(q1.x); vv[2] = q1.y;
        pk[3] = __float_as_uint(q1.z); vv[3] = q1.w;
        pk[4] = __float_as_uint(q2.x); vv[4] = q2.y;
        pk[5] = __float_as_uint(q2.z); vv[5] = q2.w;
        pk[6] = __float_as_uint(q3.x); vv[6] = q3.y;
        pk[7] = __float_as_uint(q3.z); vv[7] = q3.w;
        float w[8];
        #pragma unroll
        for (int k = 0; k < 8; ++k)
            w[k] = weight[(pk[k] & CMASK) * FEAT + f];   // 8 independent gathers
        #pragma unroll
        for (int k = 0; k < 8; ++k)
            atomicAdd(&acc[((pk[k] >> COLBITS) & (RPB - 1)) * FEAT + f],
                      vv[k] * w[k]);
    }
    for (int j = j0; j < n; ++j) {              // at most one group takes tail
        float2 r2 = p[j];
        unsigned k = __float_as_uint(r2.x);
        float w = weight[(k & CMASK) * FEAT + f];
        atomicAdd(&acc[((k >> COLBITS) & (RPB - 1)) * FEAT + f], r2.y * w);
    }
    __syncthreads();

    int row0 = b << LOG_RPB;
    int rows = n_nodes - row0;
    if (rows > RPB) rows = RPB;
    int lim = rows * FEAT / 4;
    const float4* b4 = (const float4*)bias;
    float4* o4 = (float4*)(out + (long long)row0 * FEAT);
    for (int i = threadIdx.x; i < lim; i += 512) {
        float4 a = ((const float4*)acc)[i];
        float4 bb = b4[i & 7];
        a.x += bb.x; a.y += bb.y; a.z += bb.z; a.w += bb.w;
        o4[i] = a;
    }
}

// ---------------- v2 fallback (bin + gather) ----------------

__global__ __launch_bounds__(256) void gnn_init(
    const float* __restrict__ bias, float* __restrict__ out,
    int* __restrict__ cnt, int total4, int n_nodes) {
    int i = blockIdx.x * blockDim.x + threadIdx.x;
    if (i < total4) {
        float4 bb = ((const float4*)bias)[i & 7];
        ((float4*)out)[i] = bb;
    }
    if (i < n_nodes) cnt[i] = 0;
}

__global__ __launch_bounds__(256) void gnn_bin(
    const int* __restrict__ edge_row,
    const int* __restrict__ edge_col,
    const float* __restrict__ edge_val,
    const float* __restrict__ weight,
    float2* __restrict__ bins,
    int* __restrict__ cnt,
    float* __restrict__ out,
    int num_edges, int cap) {
    int e = blockIdx.x * blockDim.x + threadIdx.x;
    if (e >= num_edges) return;
    int r = edge_row[e];
    int c = edge_col[e];
    float v = edge_val[e];
    int slot = atomicAdd(&cnt[r], 1);
    if (slot < cap) {
        bins[(long long)r * cap + slot] = make_float2(__int_as_float(c), v);
    } else {
        const float* w = weight + (long long)c * FEAT;
        #pragma unroll
        for (int f = 0; f < FEAT; ++f)
            atomicAdd(out + (long long)r * FEAT + f, v * w[f]);
    }
}

__global__ __launch_bounds__(256) void gnn_gather(
    const float2* __restrict__ bins,
    const int* __restrict__ cnt,
    const float* __restrict__ weight,
    float* __restrict__ out,
    int n_nodes, int cap) {
    int g = (blockIdx.x * blockDim.x + threadIdx.x) >> 5;
    int f = threadIdx.x & (FEAT - 1);
    if (g >= n_nodes) return;
    int n = cnt[g];
    n = n < cap ? n : cap;
    const float2* b = bins + (long long)g * cap;
    float a0 = 0.f, a1 = 0.f, a2 = 0.f, a3 = 0.f;
    int j = 0;
    for (; j + 4 <= n; j += 4) {
        float2 e0 = b[j], e1 = b[j + 1], e2 = b[j + 2], e3 = b[j + 3];
        a0 += e0.y * weight[(long long)__float_as_int(e0.x) * FEAT + f];
        a1 += e1.y * weight[(long long)__float_as_int(e1.x) * FEAT + f];
        a2 += e2.y * weight[(long long)__float_as_int(e2.x) * FEAT + f];
        a3 += e3.y * weight[(long long)__float_as_int(e3.x) * FEAT + f];
    }
    for (; j < n; ++j) {
        float2 e0 = b[j];
        a0 += e0.y * weight[(long long)__float_as_int(e0.x) * FEAT + f];
    }
    out[(long long)g * FEAT + f] += (a0 + a1) + (a2 + a3);
}

// ---------------- v0 fallback ----------------

__global__ __launch_bounds__(256) void gnn_init_out(
    const float* __restrict__ bias, float* __restrict__ out, int total) {
    int i = blockIdx.x * blockDim.x + threadIdx.x;
    if (i < total) out[i] = bias[i & (FEAT - 1)];
}

__global__ __launch_bounds__(256) void gnn_scatter(
    const int* __restrict__ edge_row,
    const int* __restrict__ edge_col,
    const float* __restrict__ edge_val,
    const float* __restrict__ weight,
    float* __restrict__ out,
    int num_edges) {
    long long t = (long long)blockIdx.x * blockDim.x + threadIdx.x;
    int e = (int)(t >> 5);
    int f = (int)(t & (FEAT - 1));
    if (e < num_edges) {
        int r = edge_row[e];
        int c = edge_col[e];
        atomicAdd(out + r * FEAT + f, edge_val[e] * weight[c * FEAT + f]);
    }
}

extern "C" void kernel_launch(void* const* d_in, const int* in_sizes, int n_in,
                              void* d_out, int out_size, void* d_ws, size_t ws_size,
                              hipStream_t stream) {
    const int*   edge_row = (const int*)d_in[0];
    const int*   edge_col = (const int*)d_in[1];
    const float* edge_val = (const float*)d_in[2];
    const float* weight   = (const float*)d_in[3];
    const float* bias     = (const float*)d_in[4];
    float* out = (float*)d_out;

    const int E = in_sizes[0];
    const int total = out_size;        // N * 32 elements
    const int N = total / FEAT;
    const int B = (N + RPB - 1) >> LOG_RPB;

    auto align256 = [](size_t x) { return (x + 255) & ~(size_t)255; };
    size_t cnt_off    = 0;
    size_t startp_off = align256(cnt_off + (size_t)B * sizeof(int));
    size_t cursor_off = align256(startp_off + (size_t)B * sizeof(int));
    size_t parts_off  = align256(cursor_off + (size_t)B * sizeof(int));
    // padded total <= E + 3*B records
    size_t need_v4 = parts_off + ((size_t)E + 3 * (size_t)B + 64) * sizeof(float2);

    if (B >= 1 && B <= BMAX && N <= (1 << COLBITS) && E > 0 && ws_size >= need_v4) {
        int* cnt      = (int*)((char*)d_ws + cnt_off);
        int* startp   = (int*)((char*)d_ws + startp_off);
        int* cursor   = (int*)((char*)d_ws + cursor_off);
        float2* parts = (float2*)((char*)d_ws + parts_off);

        gnn_zero<<<(B + 255) / 256, 256, 0, stream>>>(cnt, B);
        gnn_hist<<<(E + HCHUNK - 1) / HCHUNK, 256, 0, stream>>>(
            edge_row, cnt, E, B);
        gnn_scan<<<1, BMAX, 0, stream>>>(cnt, startp, cursor, B);
        gnn_part<<<(E + PCHUNK - 1) / PCHUNK, PTHREADS, 0, stream>>>(
            edge_row, edge_col, edge_val, cursor, parts, E, B);
        gnn_accum<<<B, 512, 0, stream>>>(
            parts, startp, cnt, weight, bias, out, N);
        return;
    }

    // v2 fallback: bin + gather
    size_t cnt_bytes = align256((size_t)N * sizeof(int));
    long long cap_ll = 0;
    if (ws_size > cnt_bytes)
        cap_ll = (long long)((ws_size - cnt_bytes) / ((size_t)N * sizeof(float2)));
    int cap = (int)(cap_ll > CAP_MAX ? CAP_MAX : cap_ll);

    if (cap >= 16) {
        int* cnt = (int*)d_ws;
        float2* bins = (float2*)((char*)d_ws + cnt_bytes);
        int total4 = total / 4;
        int init_threads = total4 > N ? total4 : N;
        gnn_init<<<(init_threads + 255) / 256, 256, 0, stream>>>(
            bias, out, cnt, total4, N);
        gnn_bin<<<(E + 255) / 256, 256, 0, stream>>>(
            edge_row, edge_col, edge_val, weight, bins, cnt, out, E, cap);
        long long gthreads = (long long)N * FEAT;
        gnn_gather<<<(int)((gthreads + 255) / 256), 256, 0, stream>>>(
            bins, cnt, weight, out, N, cap);
    } else {
        gnn_init_out<<<(total + 255) / 256, 256, 0, stream>>>(bias, out, total);
        long long threads = (long long)E * FEAT;
        gnn_scatter<<<(int)((threads + 255) / 256), 256, 0, stream>>>(
            edge_row, edge_col, edge_val, weight, out, E);
    }
}

// Round 5
// 144.450 us; speedup vs baseline: 3.3974x; 3.1200x over previous
//
#include <hip/hip_runtime.h>

// out[N,32] = segment_sum(edge_val[e] * weight[edge_col[e], :], edge_row[e]) + bias
//
// v5: coalesced 782-bucket counting sort + per-bucket in-LDS row sort +
// register-accumulate gather (NO LDS atomics on the hot path).
//   K0 gnn_zero  : cnt[B] = 0
//   K1 gnn_hist  : per-WG LDS histogram over 8192 edges -> global atomicAdd.
//   K2 gnn_scan  : 1 WG scans 4-record-PADDED counts -> startp[], cursor[].
//   K3 gnn_part  : per 4096-edge chunk: LDS hist -> scan -> reserve global runs
//                  -> LDS scatter in bucket order (record + bucket-id side array)
//                  -> direct coalesced writeout (NO binary search).
//   K4 gnn_accum : per bucket (512 thr): load <=4096 recs to REGISTERS, LDS
//                  counting-sort by row-low (hist/scan/scatter), then 16 groups
//                  x 8 rows: contiguous LDS records (broadcast reads), 8
//                  predicated independent weight gathers in flight, register
//                  accumulator, one coalesced out-row store (+bias).
//                  Rare n>4096 overflow -> global atomics after barrier.
//
// Fallbacks: v2 bin+gather if ws too small / shape out of range; v0 atomics last.

#define FEAT 32
#define LOG_RPB 7
#define RPB (1 << LOG_RPB)
#define COLBITS 17
#define CMASK ((1u << COLBITS) - 1)
#define BMAX 1024
#define HCHUNK 8192
#define PCHUNK 4096
#define PTHREADS 1024
#define CAPN 4096                    // accum in-LDS record capacity
#define CAP_MAX 32

// ---------------- v5 kernels ----------------

__global__ __launch_bounds__(256) void gnn_zero(int* __restrict__ cnt, int B) {
    int i = blockIdx.x * 256 + threadIdx.x;
    if (i < B) cnt[i] = 0;
}

__global__ __launch_bounds__(256) void gnn_hist(
    const int* __restrict__ edge_row, int* __restrict__ cnt,
    int num_edges, int B) {
    __shared__ int h[BMAX];
    for (int b = threadIdx.x; b < BMAX; b += 256) h[b] = 0;
    __syncthreads();
    int e0 = blockIdx.x * HCHUNK;
    #pragma unroll
    for (int k = 0; k < HCHUNK / 256; ++k) {
        int e = e0 + k * 256 + threadIdx.x;
        if (e < num_edges) atomicAdd(&h[edge_row[e] >> LOG_RPB], 1);
    }
    __syncthreads();
    for (int b = threadIdx.x; b < B; b += 256) {
        int c = h[b];
        if (c) atomicAdd(&cnt[b], c);
    }
}

__global__ __launch_bounds__(1024) void gnn_scan(
    const int* __restrict__ cnt, int* __restrict__ startp,
    int* __restrict__ cursor, int B) {
    __shared__ int s[BMAX];
    int t = threadIdx.x;
    int v  = (t < B) ? cnt[t] : 0;
    int pv = (v + 3) & ~3;              // pad buckets to multiples of 4 recs
    s[t] = pv;
    __syncthreads();
    for (int off = 1; off < BMAX; off <<= 1) {
        int u = (t >= off) ? s[t - off] : 0;
        __syncthreads();
        s[t] += u;
        __syncthreads();
    }
    if (t < B) {
        int st = s[t] - pv;
        startp[t] = st;
        cursor[t] = st;
    }
}

__global__ __launch_bounds__(PTHREADS) void gnn_part(
    const int* __restrict__ edge_row,
    const int* __restrict__ edge_col,
    const float* __restrict__ edge_val,
    int* __restrict__ cursor,
    float2* __restrict__ parts,
    int num_edges, int B) {
    __shared__ float2 lrec[PCHUNK];              // 32 KB
    __shared__ unsigned short lbkt[PCHUNK];      // 8 KB: bucket id per slot
    __shared__ int st[BMAX];                     // exclusive starts
    __shared__ int cur[BMAX];                    // hist, then local cursor
    __shared__ int cb[BMAX];                     // global run base
    int t = threadIdx.x;
    for (int b = t; b < BMAX; b += PTHREADS) cur[b] = 0;
    __syncthreads();

    int e0 = blockIdx.x * PCHUNK;
    int cnt_chunk = num_edges - e0;
    if (cnt_chunk > PCHUNK) cnt_chunk = PCHUNK;

    // 1) local histogram (cache rows in registers for reuse in pass 3)
    int rloc[PCHUNK / PTHREADS];
    #pragma unroll
    for (int k = 0; k < PCHUNK / PTHREADS; ++k) {
        int e = e0 + k * PTHREADS + t;
        rloc[k] = (e < num_edges) ? edge_row[e] : -1;
        if (rloc[k] >= 0) atomicAdd(&cur[rloc[k] >> LOG_RPB], 1);
    }
    __syncthreads();

    // 2) local exclusive scan + global run reservation
    int v = (t < B) ? cur[t] : 0;
    st[t] = v;
    __syncthreads();
    for (int off = 1; off < BMAX; off <<= 1) {
        int u = (t >= off) ? st[t - off] : 0;
        __syncthreads();
        st[t] += u;
        __syncthreads();
    }
    st[t] -= v;                                  // exclusive
    if (t < B) {
        cur[t] = st[t];                          // local cursor
        cb[t]  = v ? atomicAdd(&cursor[t], v) : 0;
    }
    __syncthreads();

    // 3) scatter records into LDS in bucket order, tagging bucket id
    #pragma unroll
    for (int k = 0; k < PCHUNK / PTHREADS; ++k) {
        int e = e0 + k * PTHREADS + t;
        if (rloc[k] >= 0) {
            int r = rloc[k];
            int bb = r >> LOG_RPB;
            int slot = atomicAdd(&cur[bb], 1);
            unsigned pk = (unsigned)edge_col[e] |
                          ((unsigned)(r & (RPB - 1)) << COLBITS);
            lrec[slot] = make_float2(__uint_as_float(pk), edge_val[e]);
            lbkt[slot] = (unsigned short)bb;
        }
    }
    __syncthreads();

    // 4) coalesced writeout: direct bucket lookup, no search
    for (int i = t; i < cnt_chunk; i += PTHREADS) {
        int bb = lbkt[i];
        parts[(long long)cb[bb] + (i - st[bb])] = lrec[i];
    }
}

__global__ __launch_bounds__(512) void gnn_accum(
    const float2* __restrict__ parts,
    const int* __restrict__ startp,
    const int* __restrict__ cnt,
    const float* __restrict__ weight,
    const float* __restrict__ bias,
    float* __restrict__ out,
    int n_nodes) {
    __shared__ float2 srec[CAPN];       // 32 KB: row-sorted records
    __shared__ int h[RPB];
    __shared__ int sc[RPB];
    __shared__ int rs[RPB + 1];
    __shared__ int cur[RPB];
    int b = blockIdx.x, t = threadIdx.x;
    int n = cnt[b];
    int m = n < CAPN ? n : CAPN;
    const float2* p = parts + startp[b];

    // 1) load records into registers (coalesced, 8/thread)
    float2 rec[CAPN / 512];
    #pragma unroll
    for (int k = 0; k < CAPN / 512; ++k) {
        int idx = t + k * 512;
        rec[k] = (idx < m) ? p[idx] : make_float2(0.f, 0.f);
    }

    // 2) row-low histogram
    if (t < RPB) h[t] = 0;
    __syncthreads();
    #pragma unroll
    for (int k = 0; k < CAPN / 512; ++k) {
        int idx = t + k * 512;
        if (idx < m) {
            unsigned rl = (__float_as_uint(rec[k].x) >> COLBITS) & (RPB - 1);
            atomicAdd(&h[rl], 1);
        }
    }
    __syncthreads();

    // 3) scan 128 (Hillis-Steele)
    if (t < RPB) sc[t] = h[t];
    __syncthreads();
    #pragma unroll
    for (int off = 1; off < RPB; off <<= 1) {
        int u = (t < RPB && t >= off) ? sc[t - off] : 0;
        __syncthreads();
        if (t < RPB) sc[t] += u;
        __syncthreads();
    }
    if (t < RPB) {
        rs[t + 1] = sc[t];
        cur[t] = sc[t] - h[t];
    }
    if (t == 0) rs[0] = 0;
    __syncthreads();

    // 4) scatter registers -> row-sorted LDS
    #pragma unroll
    for (int k = 0; k < CAPN / 512; ++k) {
        int idx = t + k * 512;
        if (idx < m) {
            unsigned rl = (__float_as_uint(rec[k].x) >> COLBITS) & (RPB - 1);
            int slot = atomicAdd(&cur[rl], 1);
            srec[slot] = rec[k];
        }
    }
    __syncthreads();

    // 5) register-accumulate gather: group g owns rows g*8..g*8+7
    int g = t >> 5;                     // 16 groups of 32 lanes
    int f = t & 31;
    int row0 = b << LOG_RPB;
    float bf = bias[f];
    #pragma unroll 1
    for (int rr = 0; rr < 8; ++rr) {
        int rl = (g << 3) + rr;
        int s = rs[rl], e = rs[rl + 1];
        float acc = 0.f;
        for (int j = s; j < e; j += 8) {
            #pragma unroll
            for (int k = 0; k < 8; ++k) {
                int jj = j + k;
                bool ok = jj < e;
                float2 rc = srec[ok ? jj : s];          // broadcast LDS read
                unsigned c = __float_as_uint(rc.x) & CMASK;
                float w = weight[c * FEAT + f];         // independent gathers
                acc += ok ? rc.y * w : 0.f;
            }
        }
        int r = row0 + rl;
        if (r < n_nodes)
            out[(long long)r * FEAT + f] = acc + bf;    // coalesced 128B store
    }

    // 6) rare overflow (n > CAPN): global atomics (uniform-random data: never)
    if (n > CAPN) {
        __syncthreads();
        __threadfence();
        for (int idx = CAPN + t; idx < n; idx += 512) {
            float2 rc = p[idx];
            unsigned pk = __float_as_uint(rc.x);
            int c  = (int)(pk & CMASK);
            int r  = row0 + (int)((pk >> COLBITS) & (RPB - 1));
            if (r < n_nodes) {
                const float* w = weight + (long long)c * FEAT;
                for (int ff = 0; ff < FEAT; ++ff)
                    atomicAdd(out + (long long)r * FEAT + ff, rc.y * w[ff]);
            }
        }
    }
}

// ---------------- v2 fallback (bin + gather) ----------------

__global__ __launch_bounds__(256) void gnn_init(
    const float* __restrict__ bias, float* __restrict__ out,
    int* __restrict__ cnt, int total4, int n_nodes) {
    int i = blockIdx.x * blockDim.x + threadIdx.x;
    if (i < total4) {
        float4 bb = ((const float4*)bias)[i & 7];
        ((float4*)out)[i] = bb;
    }
    if (i < n_nodes) cnt[i] = 0;
}

__global__ __launch_bounds__(256) void gnn_bin(
    const int* __restrict__ edge_row,
    const int* __restrict__ edge_col,
    const float* __restrict__ edge_val,
    const float* __restrict__ weight,
    float2* __restrict__ bins,
    int* __restrict__ cnt,
    float* __restrict__ out,
    int num_edges, int cap) {
    int e = blockIdx.x * blockDim.x + threadIdx.x;
    if (e >= num_edges) return;
    int r = edge_row[e];
    int c = edge_col[e];
    float v = edge_val[e];
    int slot = atomicAdd(&cnt[r], 1);
    if (slot < cap) {
        bins[(long long)r * cap + slot] = make_float2(__int_as_float(c), v);
    } else {
        const float* w = weight + (long long)c * FEAT;
        #pragma unroll
        for (int f = 0; f < FEAT; ++f)
            atomicAdd(out + (long long)r * FEAT + f, v * w[f]);
    }
}

__global__ __launch_bounds__(256) void gnn_gather(
    const float2* __restrict__ bins,
    const int* __restrict__ cnt,
    const float* __restrict__ weight,
    float* __restrict__ out,
    int n_nodes, int cap) {
    int g = (blockIdx.x * blockDim.x + threadIdx.x) >> 5;
    int f = threadIdx.x & (FEAT - 1);
    if (g >= n_nodes) return;
    int n = cnt[g];
    n = n < cap ? n : cap;
    const float2* b = bins + (long long)g * cap;
    float a0 = 0.f, a1 = 0.f, a2 = 0.f, a3 = 0.f;
    int j = 0;
    for (; j + 4 <= n; j += 4) {
        float2 e0 = b[j], e1 = b[j + 1], e2 = b[j + 2], e3 = b[j + 3];
        a0 += e0.y * weight[(long long)__float_as_int(e0.x) * FEAT + f];
        a1 += e1.y * weight[(long long)__float_as_int(e1.x) * FEAT + f];
        a2 += e2.y * weight[(long long)__float_as_int(e2.x) * FEAT + f];
        a3 += e3.y * weight[(long long)__float_as_int(e3.x) * FEAT + f];
    }
    for (; j < n; ++j) {
        float2 e0 = b[j];
        a0 += e0.y * weight[(long long)__float_as_int(e0.x) * FEAT + f];
    }
    out[(long long)g * FEAT + f] += (a0 + a1) + (a2 + a3);
}

// ---------------- v0 fallback ----------------

__global__ __launch_bounds__(256) void gnn_init_out(
    const float* __restrict__ bias, float* __restrict__ out, int total) {
    int i = blockIdx.x * blockDim.x + threadIdx.x;
    if (i < total) out[i] = bias[i & (FEAT - 1)];
}

__global__ __launch_bounds__(256) void gnn_scatter(
    const int* __restrict__ edge_row,
    const int* __restrict__ edge_col,
    const float* __restrict__ edge_val,
    const float* __restrict__ weight,
    float* __restrict__ out,
    int num_edges) {
    long long t = (long long)blockIdx.x * blockDim.x + threadIdx.x;
    int e = (int)(t >> 5);
    int f = (int)(t & (FEAT - 1));
    if (e < num_edges) {
        int r = edge_row[e];
        int c = edge_col[e];
        atomicAdd(out + r * FEAT + f, edge_val[e] * weight[c * FEAT + f]);
    }
}

extern "C" void kernel_launch(void* const* d_in, const int* in_sizes, int n_in,
                              void* d_out, int out_size, void* d_ws, size_t ws_size,
                              hipStream_t stream) {
    const int*   edge_row = (const int*)d_in[0];
    const int*   edge_col = (const int*)d_in[1];
    const float* edge_val = (const float*)d_in[2];
    const float* weight   = (const float*)d_in[3];
    const float* bias     = (const float*)d_in[4];
    float* out = (float*)d_out;

    const int E = in_sizes[0];
    const int total = out_size;        // N * 32 elements
    const int N = total / FEAT;
    const int B = (N + RPB - 1) >> LOG_RPB;

    auto align256 = [](size_t x) { return (x + 255) & ~(size_t)255; };
    size_t cnt_off    = 0;
    size_t startp_off = align256(cnt_off + (size_t)B * sizeof(int));
    size_t cursor_off = align256(startp_off + (size_t)B * sizeof(int));
    size_t parts_off  = align256(cursor_off + (size_t)B * sizeof(int));
    size_t need_v5 = parts_off + ((size_t)E + 3 * (size_t)B + 64) * sizeof(float2);

    if (B >= 1 && B <= BMAX && N <= (1 << COLBITS) && E > 0 && ws_size >= need_v5) {
        int* cnt      = (int*)((char*)d_ws + cnt_off);
        int* startp   = (int*)((char*)d_ws + startp_off);
        int* cursor   = (int*)((char*)d_ws + cursor_off);
        float2* parts = (float2*)((char*)d_ws + parts_off);

        gnn_zero<<<(B + 255) / 256, 256, 0, stream>>>(cnt, B);
        gnn_hist<<<(E + HCHUNK - 1) / HCHUNK, 256, 0, stream>>>(
            edge_row, cnt, E, B);
        gnn_scan<<<1, BMAX, 0, stream>>>(cnt, startp, cursor, B);
        gnn_part<<<(E + PCHUNK - 1) / PCHUNK, PTHREADS, 0, stream>>>(
            edge_row, edge_col, edge_val, cursor, parts, E, B);
        gnn_accum<<<B, 512, 0, stream>>>(
            parts, startp, cnt, weight, bias, out, N);
        return;
    }

    // v2 fallback: bin + gather
    size_t cnt_bytes = align256((size_t)N * sizeof(int));
    long long cap_ll = 0;
    if (ws_size > cnt_bytes)
        cap_ll = (long long)((ws_size - cnt_bytes) / ((size_t)N * sizeof(float2)));
    int cap = (int)(cap_ll > CAP_MAX ? CAP_MAX : cap_ll);

    if (cap >= 16) {
        int* cnt = (int*)d_ws;
        float2* bins = (float2*)((char*)d_ws + cnt_bytes);
        int total4 = total / 4;
        int init_threads = total4 > N ? total4 : N;
        gnn_init<<<(init_threads + 255) / 256, 256, 0, stream>>>(
            bias, out, cnt, total4, N);
        gnn_bin<<<(E + 255) / 256, 256, 0, stream>>>(
            edge_row, edge_col, edge_val, weight, bins, cnt, out, E, cap);
        long long gthreads = (long long)N * FEAT;
        gnn_gather<<<(int)((gthreads + 255) / 256), 256, 0, stream>>>(
            bins, cnt, weight, out, N, cap);
    } else {
        gnn_init_out<<<(total + 255) / 256, 256, 0, stream>>>(bias, out, total);
        long long threads = (long long)E * FEAT;
        gnn_scatter<<<(int)((threads + 255) / 256), 256, 0, stream>>>(
            edge_row, edge_col, edge_val, weight, out, E);
    }
}

// Round 6
// 126.425 us; speedup vs baseline: 3.8818x; 1.1426x over previous
//
#include <hip/hip_runtime.h>

// out[N,32] = segment_sum(edge_val[e] * weight[edge_col[e], :], edge_row[e]) + bias
//
// v6: single-pass fixed-capacity bucket partition + per-bucket in-LDS row sort +
// register-accumulate gather. Deletes v5's global hist + single-WG scan.
//   Buckets of RPB=128 rows, fixed CAPB=2560 record slots (mean 2046, +11 sigma).
//   K0 gnn_zero  : cursor[B] = 0, scnt = 0.
//   K1 gnn_part  : per 4096-edge chunk (1024 thr, int4/float4 edge loads):
//                  LDS hist -> local scan -> reserve run base via
//                  atomicAdd(cursor[b], localcount) -> LDS scatter in bucket
//                  order (+bucket tag) -> coalesced writeout to
//                  parts[b*CAPB + slot]. Slots >= CAPB go to an exact global
//                  spill list (never taken for uniform data, correct always).
//   K2 gnn_accum : per bucket (512 thr): load <=CAPB recs to REGISTERS, LDS
//                  counting-sort by row-low, then 16 groups x 8 rows:
//                  contiguous broadcast LDS reads, 8 independent weight
//                  gathers in flight, register acc, coalesced out store +bias.
//   K3 gnn_spill : applies spill entries with global atomics (scnt==0 -> exit).
//
// Fallbacks: v2 bin+gather if ws too small / shape out of range; v0 atomics last.

#define FEAT 32
#define LOG_RPB 7
#define RPB (1 << LOG_RPB)
#define COLBITS 17
#define CMASK ((1u << COLBITS) - 1)
#define BMAX 1024
#define PCHUNK 4096
#define PTHREADS 1024
#define EPT (PCHUNK / PTHREADS)      // 4 edges per thread
#define CAPB 2560                    // record slots per bucket (mult of 512)
#define CAP_MAX 32

// ---------------- v6 kernels ----------------

__global__ __launch_bounds__(256) void gnn_zero(
    int* __restrict__ cursor, int* __restrict__ scnt, int B) {
    int i = blockIdx.x * 256 + threadIdx.x;
    if (i < B) cursor[i] = 0;
    if (i == B) *scnt = 0;
}

__global__ __launch_bounds__(PTHREADS) void gnn_part(
    const int* __restrict__ edge_row,
    const int* __restrict__ edge_col,
    const float* __restrict__ edge_val,
    int* __restrict__ cursor,
    float2* __restrict__ parts,
    float4* __restrict__ spill,
    int* __restrict__ scnt,
    int num_edges, int B) {
    __shared__ float2 lrec[PCHUNK];              // 32 KB
    __shared__ unsigned short lbkt[PCHUNK];      // 8 KB
    __shared__ int st[BMAX];                     // local exclusive starts
    __shared__ int cur[BMAX];                    // hist, then local cursor
    __shared__ int rb[BMAX];                     // global run base (slot index)
    int t = threadIdx.x;
    for (int b = t; b < BMAX; b += PTHREADS) cur[b] = 0;
    __syncthreads();

    int e0 = blockIdx.x * PCHUNK;
    int cnt_chunk = num_edges - e0;
    if (cnt_chunk > PCHUNK) cnt_chunk = PCHUNK;

    // 1) vectorized edge loads (4 consecutive edges per lane) + local histogram
    int  r[EPT], c[EPT];
    float vv[EPT];
    int ebase = e0 + 4 * t;
    if (ebase + 3 < num_edges) {
        int4  r4 = *(const int4*)(edge_row + ebase);
        int4  c4 = *(const int4*)(edge_col + ebase);
        float4 v4 = *(const float4*)(edge_val + ebase);
        r[0] = r4.x; r[1] = r4.y; r[2] = r4.z; r[3] = r4.w;
        c[0] = c4.x; c[1] = c4.y; c[2] = c4.z; c[3] = c4.w;
        vv[0] = v4.x; vv[1] = v4.y; vv[2] = v4.z; vv[3] = v4.w;
    } else {
        #pragma unroll
        for (int k = 0; k < EPT; ++k) {
            int e = ebase + k;
            bool ok = e < num_edges;
            r[k]  = ok ? edge_row[e] : -1;
            c[k]  = ok ? edge_col[e] : 0;
            vv[k] = ok ? edge_val[e] : 0.f;
        }
    }
    #pragma unroll
    for (int k = 0; k < EPT; ++k)
        if (r[k] >= 0) atomicAdd(&cur[r[k] >> LOG_RPB], 1);
    __syncthreads();

    // 2) local exclusive scan + global run reservation (no global scan needed:
    //    buckets have fixed stride CAPB)
    int v = (t < B) ? cur[t] : 0;
    st[t] = v;
    __syncthreads();
    for (int off = 1; off < BMAX; off <<= 1) {
        int u = (t >= off) ? st[t - off] : 0;
        __syncthreads();
        st[t] += u;
        __syncthreads();
    }
    st[t] -= v;                                  // exclusive
    if (t < B) {
        cur[t] = st[t];                          // local cursor
        rb[t]  = v ? atomicAdd(&cursor[t], v) : 0;
    }
    __syncthreads();

    // 3) scatter records into LDS in bucket order, tagging bucket id
    #pragma unroll
    for (int k = 0; k < EPT; ++k) {
        if (r[k] >= 0) {
            int bb = r[k] >> LOG_RPB;
            int slot = atomicAdd(&cur[bb], 1);
            unsigned pk = (unsigned)c[k] |
                          ((unsigned)(r[k] & (RPB - 1)) << COLBITS);
            lrec[slot] = make_float2(__uint_as_float(pk), vv[k]);
            lbkt[slot] = (unsigned short)bb;
        }
    }
    __syncthreads();

    // 4) coalesced writeout (consecutive i -> consecutive slots of one bucket)
    for (int i = t; i < cnt_chunk; i += PTHREADS) {
        int bb = lbkt[i];
        float2 rec = lrec[i];
        int s = rb[bb] + (i - st[bb]);
        if (s < CAPB) {
            parts[(long long)bb * CAPB + s] = rec;
        } else {
            // exact overflow path (never taken for uniform data)
            int si = atomicAdd(scnt, 1);
            unsigned pk = __float_as_uint(rec.x);
            spill[si] = make_float4(
                __uint_as_float((unsigned)(bb << LOG_RPB) + (pk >> COLBITS)),
                __uint_as_float(pk & CMASK), rec.y, 0.f);
        }
    }
}

__global__ __launch_bounds__(512) void gnn_accum(
    const float2* __restrict__ parts,
    const int* __restrict__ cursor,
    const float* __restrict__ weight,
    const float* __restrict__ bias,
    float* __restrict__ out,
    int n_nodes) {
    __shared__ float2 srec[CAPB];       // 20 KB: row-sorted records
    __shared__ int h[RPB];
    __shared__ int sc[RPB];
    __shared__ int rs[RPB + 1];
    __shared__ int cur[RPB];
    int b = blockIdx.x, t = threadIdx.x;
    int n = cursor[b];
    int m = n < CAPB ? n : CAPB;
    const float2* p = parts + (long long)b * CAPB;

    // 1) load records into registers (coalesced, 5/thread)
    float2 rec[CAPB / 512];
    #pragma unroll
    for (int k = 0; k < CAPB / 512; ++k) {
        int idx = t + k * 512;
        rec[k] = (idx < m) ? p[idx] : make_float2(0.f, 0.f);
    }

    // 2) row-low histogram
    if (t < RPB) h[t] = 0;
    __syncthreads();
    #pragma unroll
    for (int k = 0; k < CAPB / 512; ++k) {
        int idx = t + k * 512;
        if (idx < m) {
            unsigned rl = (__float_as_uint(rec[k].x) >> COLBITS) & (RPB - 1);
            atomicAdd(&h[rl], 1);
        }
    }
    __syncthreads();

    // 3) scan 128 (Hillis-Steele)
    if (t < RPB) sc[t] = h[t];
    __syncthreads();
    #pragma unroll
    for (int off = 1; off < RPB; off <<= 1) {
        int u = (t < RPB && t >= off) ? sc[t - off] : 0;
        __syncthreads();
        if (t < RPB) sc[t] += u;
        __syncthreads();
    }
    if (t < RPB) {
        rs[t + 1] = sc[t];
        cur[t] = sc[t] - h[t];
    }
    if (t == 0) rs[0] = 0;
    __syncthreads();

    // 4) scatter registers -> row-sorted LDS
    #pragma unroll
    for (int k = 0; k < CAPB / 512; ++k) {
        int idx = t + k * 512;
        if (idx < m) {
            unsigned rl = (__float_as_uint(rec[k].x) >> COLBITS) & (RPB - 1);
            int slot = atomicAdd(&cur[rl], 1);
            srec[slot] = rec[k];
        }
    }
    __syncthreads();

    // 5) register-accumulate gather: group g owns rows g*8..g*8+7
    int g = t >> 5;                     // 16 groups of 32 lanes
    int f = t & 31;
    int row0 = b << LOG_RPB;
    float bf = bias[f];
    #pragma unroll 1
    for (int rr = 0; rr < 8; ++rr) {
        int rl = (g << 3) + rr;
        int s = rs[rl], e = rs[rl + 1];
        float acc = 0.f;
        for (int j = s; j < e; j += 8) {
            #pragma unroll
            for (int k = 0; k < 8; ++k) {
                int jj = j + k;
                bool ok = jj < e;
                float2 rc = srec[ok ? jj : s];          // broadcast LDS read
                unsigned cc = __float_as_uint(rc.x) & CMASK;
                float w = weight[cc * FEAT + f];        // independent gathers
                acc += ok ? rc.y * w : 0.f;
            }
        }
        int rrow = row0 + rl;
        if (rrow < n_nodes)
            out[(long long)rrow * FEAT + f] = acc + bf; // coalesced 128B store
    }
}

__global__ __launch_bounds__(256) void gnn_spill(
    const float4* __restrict__ spill,
    const int* __restrict__ scnt,
    const float* __restrict__ weight,
    float* __restrict__ out,
    int n_nodes) {
    int total = *scnt;
    int idx = (blockIdx.x * 256 + threadIdx.x) >> 5;
    int f = threadIdx.x & 31;
    int stride = (gridDim.x * 256) >> 5;
    for (; idx < total; idx += stride) {
        float4 s = spill[idx];
        int r = (int)__float_as_uint(s.x);
        int c = (int)__float_as_uint(s.y);
        if (r < n_nodes)
            atomicAdd(out + (long long)r * FEAT + f,
                      s.z * weight[(long long)c * FEAT + f]);
    }
}

// ---------------- v2 fallback (bin + gather) ----------------

__global__ __launch_bounds__(256) void gnn_init(
    const float* __restrict__ bias, float* __restrict__ out,
    int* __restrict__ cnt, int total4, int n_nodes) {
    int i = blockIdx.x * blockDim.x + threadIdx.x;
    if (i < total4) {
        float4 bb = ((const float4*)bias)[i & 7];
        ((float4*)out)[i] = bb;
    }
    if (i < n_nodes) cnt[i] = 0;
}

__global__ __launch_bounds__(256) void gnn_bin(
    const int* __restrict__ edge_row,
    const int* __restrict__ edge_col,
    const float* __restrict__ edge_val,
    const float* __restrict__ weight,
    float2* __restrict__ bins,
    int* __restrict__ cnt,
    float* __restrict__ out,
    int num_edges, int cap) {
    int e = blockIdx.x * blockDim.x + threadIdx.x;
    if (e >= num_edges) return;
    int r = edge_row[e];
    int c = edge_col[e];
    float v = edge_val[e];
    int slot = atomicAdd(&cnt[r], 1);
    if (slot < cap) {
        bins[(long long)r * cap + slot] = make_float2(__int_as_float(c), v);
    } else {
        const float* w = weight + (long long)c * FEAT;
        #pragma unroll
        for (int f = 0; f < FEAT; ++f)
            atomicAdd(out + (long long)r * FEAT + f, v * w[f]);
    }
}

__global__ __launch_bounds__(256) void gnn_gather(
    const float2* __restrict__ bins,
    const int* __restrict__ cnt,
    const float* __restrict__ weight,
    float* __restrict__ out,
    int n_nodes, int cap) {
    int g = (blockIdx.x * blockDim.x + threadIdx.x) >> 5;
    int f = threadIdx.x & (FEAT - 1);
    if (g >= n_nodes) return;
    int n = cnt[g];
    n = n < cap ? n : cap;
    const float2* b = bins + (long long)g * cap;
    float a0 = 0.f, a1 = 0.f, a2 = 0.f, a3 = 0.f;
    int j = 0;
    for (; j + 4 <= n; j += 4) {
        float2 e0 = b[j], e1 = b[j + 1], e2 = b[j + 2], e3 = b[j + 3];
        a0 += e0.y * weight[(long long)__float_as_int(e0.x) * FEAT + f];
        a1 += e1.y * weight[(long long)__float_as_int(e1.x) * FEAT + f];
        a2 += e2.y * weight[(long long)__float_as_int(e2.x) * FEAT + f];
        a3 += e3.y * weight[(long long)__float_as_int(e3.x) * FEAT + f];
    }
    for (; j < n; ++j) {
        float2 e0 = b[j];
        a0 += e0.y * weight[(long long)__float_as_int(e0.x) * FEAT + f];
    }
    out[(long long)g * FEAT + f] += (a0 + a1) + (a2 + a3);
}

// ---------------- v0 fallback ----------------

__global__ __launch_bounds__(256) void gnn_init_out(
    const float* __restrict__ bias, float* __restrict__ out, int total) {
    int i = blockIdx.x * blockDim.x + threadIdx.x;
    if (i < total) out[i] = bias[i & (FEAT - 1)];
}

__global__ __launch_bounds__(256) void gnn_scatter(
    const int* __restrict__ edge_row,
    const int* __restrict__ edge_col,
    const float* __restrict__ edge_val,
    const float* __restrict__ weight,
    float* __restrict__ out,
    int num_edges) {
    long long t = (long long)blockIdx.x * blockDim.x + threadIdx.x;
    int e = (int)(t >> 5);
    int f = (int)(t & (FEAT - 1));
    if (e < num_edges) {
        int r = edge_row[e];
        int c = edge_col[e];
        atomicAdd(out + r * FEAT + f, edge_val[e] * weight[c * FEAT + f]);
    }
}

extern "C" void kernel_launch(void* const* d_in, const int* in_sizes, int n_in,
                              void* d_out, int out_size, void* d_ws, size_t ws_size,
                              hipStream_t stream) {
    const int*   edge_row = (const int*)d_in[0];
    const int*   edge_col = (const int*)d_in[1];
    const float* edge_val = (const float*)d_in[2];
    const float* weight   = (const float*)d_in[3];
    const float* bias     = (const float*)d_in[4];
    float* out = (float*)d_out;

    const int E = in_sizes[0];
    const int total = out_size;        // N * 32 elements
    const int N = total / FEAT;
    const int B = (N + RPB - 1) >> LOG_RPB;

    auto align256 = [](size_t x) { return (x + 255) & ~(size_t)255; };
    size_t cursor_off = 0;
    size_t scnt_off   = align256(cursor_off + (size_t)B * sizeof(int));
    size_t spill_off  = align256(scnt_off + sizeof(int));
    size_t parts_off  = align256(spill_off + (size_t)E * sizeof(float4));
    size_t need_v6    = parts_off + (size_t)B * CAPB * sizeof(float2);

    if (B >= 1 && B <= BMAX && N <= (1 << COLBITS) && E > 0 && ws_size >= need_v6) {
        int*    cursor = (int*)((char*)d_ws + cursor_off);
        int*    scnt   = (int*)((char*)d_ws + scnt_off);
        float4* spill  = (float4*)((char*)d_ws + spill_off);
        float2* parts  = (float2*)((char*)d_ws + parts_off);

        gnn_zero<<<(B + 1 + 255) / 256, 256, 0, stream>>>(cursor, scnt, B);
        gnn_part<<<(E + PCHUNK - 1) / PCHUNK, PTHREADS, 0, stream>>>(
            edge_row, edge_col, edge_val, cursor, parts, spill, scnt, E, B);
        gnn_accum<<<B, 512, 0, stream>>>(
            parts, cursor, weight, bias, out, N);
        gnn_spill<<<32, 256, 0, stream>>>(spill, scnt, weight, out, N);
        return;
    }

    // v2 fallback: bin + gather
    size_t cnt_bytes = align256((size_t)N * sizeof(int));
    long long cap_ll = 0;
    if (ws_size > cnt_bytes)
        cap_ll = (long long)((ws_size - cnt_bytes) / ((size_t)N * sizeof(float2)));
    int cap = (int)(cap_ll > CAP_MAX ? CAP_MAX : cap_ll);

    if (cap >= 16) {
        int* cnt = (int*)d_ws;
        float2* bins = (float2*)((char*)d_ws + cnt_bytes);
        int total4 = total / 4;
        int init_threads = total4 > N ? total4 : N;
        gnn_init<<<(init_threads + 255) / 256, 256, 0, stream>>>(
            bias, out, cnt, total4, N);
        gnn_bin<<<(E + 255) / 256, 256, 0, stream>>>(
            edge_row, edge_col, edge_val, weight, bins, cnt, out, E, cap);
        long long gthreads = (long long)N * FEAT;
        gnn_gather<<<(int)((gthreads + 255) / 256), 256, 0, stream>>>(
            bins, cnt, weight, out, N, cap);
    } else {
        gnn_init_out<<<(total + 255) / 256, 256, 0, stream>>>(bias, out, total);
        long long threads = (long long)E * FEAT;
        gnn_scatter<<<(int)((threads + 255) / 256), 256, 0, stream>>>(
            edge_row, edge_col, edge_val, weight, out, E);
    }
}

// Round 7
// 125.549 us; speedup vs baseline: 3.9089x; 1.0070x over previous
//
#include <hip/hip_runtime.h>

// out[N,32] = segment_sum(edge_val[e] * weight[edge_col[e], :], edge_row[e]) + bias
//
// v7: v6 structure (fixed-capacity 128-row buckets, coalesced LDS-sorted
// partition, per-bucket in-LDS row sort + register-accumulate gather) with the
// sort machinery slimmed:
//   - slot-fused counting sort: the histogram atomicAdd RETURNS each record's
//     in-bucket rank -> the scatter pass needs no atomics (part: -4096 LDS
//     atomics/WG; accum: -2560).
//   - accum's 128-wide Hillis-Steele scan (14 barriers) -> single wave-0
//     __shfl_up scan (2 barriers).
//   - gnn_spill folded into gnn_accum (each WG merges spill entries for its
//     own rows before its non-atomic store); 4 kernels -> 3.
//   K0 gnn_zero : cursor[B]=0, scnt=0
//   K1 gnn_part : per 4096-edge chunk (1024 thr): vector edge loads, fused
//                 hist+slot, 1024-wide scan, global run reservation, LDS
//                 scatter (no atomics), coalesced writeout; overflow -> spill.
//   K2 gnn_accum: per bucket (512 thr): regs load, fused hist+slot, wave scan,
//                 scatter (no atomics), 16 groups x 8 rows register gather
//                 (8 independent weight gathers in flight), spill merge,
//                 coalesced out store (+bias).
//
// Fallbacks: v2 bin+gather if ws too small / shape out of range; v0 atomics last.

#define FEAT 32
#define LOG_RPB 7
#define RPB (1 << LOG_RPB)
#define COLBITS 17
#define CMASK ((1u << COLBITS) - 1)
#define BMAX 1024
#define PCHUNK 4096
#define PTHREADS 1024
#define EPT (PCHUNK / PTHREADS)      // 4 edges per thread
#define CAPB 2560                    // record slots per bucket (mult of 512)
#define CAP_MAX 32

// ---------------- v7 kernels ----------------

__global__ __launch_bounds__(256) void gnn_zero(
    int* __restrict__ cursor, int* __restrict__ scnt, int B) {
    int i = blockIdx.x * 256 + threadIdx.x;
    if (i < B) cursor[i] = 0;
    if (i == B) *scnt = 0;
}

__global__ __launch_bounds__(PTHREADS) void gnn_part(
    const int* __restrict__ edge_row,
    const int* __restrict__ edge_col,
    const float* __restrict__ edge_val,
    int* __restrict__ cursor,
    float2* __restrict__ parts,
    float4* __restrict__ spill,
    int* __restrict__ scnt,
    int num_edges, int B) {
    __shared__ float2 lrec[PCHUNK];              // 32 KB
    __shared__ unsigned short lbkt[PCHUNK];      // 8 KB
    __shared__ int hcur[BMAX];                   // hist+slots, then run base
    __shared__ int st[BMAX];                     // scan -> exclusive starts
    int t = threadIdx.x;
    hcur[t] = 0;
    __syncthreads();

    int e0 = blockIdx.x * PCHUNK;
    int cnt_chunk = num_edges - e0;
    if (cnt_chunk > PCHUNK) cnt_chunk = PCHUNK;

    // 1) vectorized edge loads + fused histogram/slot assignment
    int  r[EPT], c[EPT], bb[EPT], slot[EPT];
    float vv[EPT];
    int ebase = e0 + 4 * t;
    if (ebase + 3 < num_edges) {
        int4  r4 = *(const int4*)(edge_row + ebase);
        int4  c4 = *(const int4*)(edge_col + ebase);
        float4 v4 = *(const float4*)(edge_val + ebase);
        r[0] = r4.x; r[1] = r4.y; r[2] = r4.z; r[3] = r4.w;
        c[0] = c4.x; c[1] = c4.y; c[2] = c4.z; c[3] = c4.w;
        vv[0] = v4.x; vv[1] = v4.y; vv[2] = v4.z; vv[3] = v4.w;
    } else {
        #pragma unroll
        for (int k = 0; k < EPT; ++k) {
            int e = ebase + k;
            bool ok = e < num_edges;
            r[k]  = ok ? edge_row[e] : -1;
            c[k]  = ok ? edge_col[e] : 0;
            vv[k] = ok ? edge_val[e] : 0.f;
        }
    }
    #pragma unroll
    for (int k = 0; k < EPT; ++k) {
        if (r[k] >= 0) {
            bb[k] = r[k] >> LOG_RPB;
            slot[k] = atomicAdd(&hcur[bb[k]], 1);   // rank within bucket
        }
    }
    __syncthreads();

    // 2) 1024-wide exclusive scan of counts + global run reservation
    int v = hcur[t];
    st[t] = v;
    __syncthreads();
    #pragma unroll
    for (int off = 1; off < BMAX; off <<= 1) {
        int u = (t >= off) ? st[t - off] : 0;
        __syncthreads();
        st[t] += u;
        __syncthreads();
    }
    int ex = st[t] - v;                          // own element only
    st[t] = ex;
    int rbase = 0;
    if (t < B && v) rbase = atomicAdd(&cursor[t], v);
    hcur[t] = rbase;                             // reuse as global run base
    __syncthreads();

    // 3) scatter into LDS in bucket order — NO atomics (slot known)
    #pragma unroll
    for (int k = 0; k < EPT; ++k) {
        if (r[k] >= 0) {
            int pos = st[bb[k]] + slot[k];
            unsigned pk = (unsigned)c[k] |
                          ((unsigned)(r[k] & (RPB - 1)) << COLBITS);
            lrec[pos] = make_float2(__uint_as_float(pk), vv[k]);
            lbkt[pos] = (unsigned short)bb[k];
        }
    }
    __syncthreads();

    // 4) coalesced writeout (consecutive i -> consecutive slots of one bucket)
    for (int i = t; i < cnt_chunk; i += PTHREADS) {
        int b2 = lbkt[i];
        float2 rec = lrec[i];
        int s = hcur[b2] + (i - st[b2]);
        if (s < CAPB) {
            parts[(long long)b2 * CAPB + s] = rec;
        } else {
            // exact overflow path (never taken for uniform data)
            int si = atomicAdd(scnt, 1);
            unsigned pk = __float_as_uint(rec.x);
            spill[si] = make_float4(
                __uint_as_float((unsigned)(b2 << LOG_RPB) + (pk >> COLBITS)),
                __uint_as_float(pk & CMASK), rec.y, 0.f);
        }
    }
}

__global__ __launch_bounds__(512) void gnn_accum(
    const float2* __restrict__ parts,
    const int* __restrict__ cursor,
    const int* __restrict__ scnt,
    const float4* __restrict__ spill,
    const float* __restrict__ weight,
    const float* __restrict__ bias,
    float* __restrict__ out,
    int n_nodes) {
    __shared__ float2 srec[CAPB];       // 20 KB: row-sorted records
    __shared__ int h[RPB];
    __shared__ int rs[RPB + 1];
    int b = blockIdx.x, t = threadIdx.x;
    int n = cursor[b];
    int nspill = *scnt;                 // uniform; 0 in the common case
    int m = n < CAPB ? n : CAPB;
    const float2* p = parts + (long long)b * CAPB;

    // 1) load records to registers + fused row histogram/slot
    float2 rec[CAPB / 512];
    int rl[CAPB / 512], slot[CAPB / 512];
    if (t < RPB) h[t] = 0;
    __syncthreads();
    #pragma unroll
    for (int k = 0; k < CAPB / 512; ++k) {
        int idx = t + k * 512;
        bool ok = idx < m;
        rec[k] = ok ? p[idx] : make_float2(0.f, 0.f);
        if (ok) {
            rl[k] = (int)((__float_as_uint(rec[k].x) >> COLBITS) & (RPB - 1));
            slot[k] = atomicAdd(&h[rl[k]], 1);     // rank within row
        }
    }
    __syncthreads();

    // 2) wave-0 scan of 128 row counts via shfl (2 elems/lane)
    if (t < 64) {
        int a  = h[2 * t];
        int c2 = h[2 * t + 1];
        int pr = a + c2;
        int x = pr;
        #pragma unroll
        for (int off = 1; off < 64; off <<= 1) {
            int y = __shfl_up(x, off);
            if (t >= off) x += y;
        }
        int exc = x - pr;
        rs[2 * t] = exc;
        rs[2 * t + 1] = exc + a;
        if (t == 63) rs[RPB] = x;
    }
    __syncthreads();

    // 3) scatter registers -> row-sorted LDS — NO atomics
    #pragma unroll
    for (int k = 0; k < CAPB / 512; ++k) {
        int idx = t + k * 512;
        if (idx < m) srec[rs[rl[k]] + slot[k]] = rec[k];
    }
    __syncthreads();

    // 4) register-accumulate gather: group g owns rows g*8..g*8+7
    int g = t >> 5;                     // 16 groups of 32 lanes
    int f = t & 31;
    int row0 = b << LOG_RPB;
    float bf = bias[f];
    #pragma unroll 1
    for (int rr = 0; rr < 8; ++rr) {
        int rlc = (g << 3) + rr;
        int s = rs[rlc], e = rs[rlc + 1];
        float acc = 0.f;
        for (int j = s; j < e; j += 8) {
            float2 rc[8];
            float w[8];
            #pragma unroll
            for (int k = 0; k < 8; ++k) {
                int jj = j + k;
                rc[k] = srec[jj < e ? jj : s];      // broadcast LDS read
            }
            #pragma unroll
            for (int k = 0; k < 8; ++k)
                w[k] = weight[(__float_as_uint(rc[k].x) & CMASK) * FEAT + f];
            #pragma unroll
            for (int k = 0; k < 8; ++k)
                acc += (j + k < e) ? rc[k].y * w[k] : 0.f;
        }
        // merge rare spill entries for this row (nspill==0 normally)
        if (nspill > 0) {
            for (int i = 0; i < nspill; ++i) {
                float4 sp = spill[i];
                if ((int)__float_as_uint(sp.x) == row0 + rlc)
                    acc += sp.z *
                           weight[__float_as_uint(sp.y) * FEAT + f];
            }
        }
        int rrow = row0 + rlc;
        if (rrow < n_nodes)
            out[(long long)rrow * FEAT + f] = acc + bf; // coalesced 128B store
    }
}

// ---------------- v2 fallback (bin + gather) ----------------

__global__ __launch_bounds__(256) void gnn_init(
    const float* __restrict__ bias, float* __restrict__ out,
    int* __restrict__ cnt, int total4, int n_nodes) {
    int i = blockIdx.x * blockDim.x + threadIdx.x;
    if (i < total4) {
        float4 bb = ((const float4*)bias)[i & 7];
        ((float4*)out)[i] = bb;
    }
    if (i < n_nodes) cnt[i] = 0;
}

__global__ __launch_bounds__(256) void gnn_bin(
    const int* __restrict__ edge_row,
    const int* __restrict__ edge_col,
    const float* __restrict__ edge_val,
    const float* __restrict__ weight,
    float2* __restrict__ bins,
    int* __restrict__ cnt,
    float* __restrict__ out,
    int num_edges, int cap) {
    int e = blockIdx.x * blockDim.x + threadIdx.x;
    if (e >= num_edges) return;
    int r = edge_row[e];
    int c = edge_col[e];
    float v = edge_val[e];
    int slot = atomicAdd(&cnt[r], 1);
    if (slot < cap) {
        bins[(long long)r * cap + slot] = make_float2(__int_as_float(c), v);
    } else {
        const float* w = weight + (long long)c * FEAT;
        #pragma unroll
        for (int f = 0; f < FEAT; ++f)
            atomicAdd(out + (long long)r * FEAT + f, v * w[f]);
    }
}

__global__ __launch_bounds__(256) void gnn_gather(
    const float2* __restrict__ bins,
    const int* __restrict__ cnt,
    const float* __restrict__ weight,
    float* __restrict__ out,
    int n_nodes, int cap) {
    int g = (blockIdx.x * blockDim.x + threadIdx.x) >> 5;
    int f = threadIdx.x & (FEAT - 1);
    if (g >= n_nodes) return;
    int n = cnt[g];
    n = n < cap ? n : cap;
    const float2* b = bins + (long long)g * cap;
    float a0 = 0.f, a1 = 0.f, a2 = 0.f, a3 = 0.f;
    int j = 0;
    for (; j + 4 <= n; j += 4) {
        float2 e0 = b[j], e1 = b[j + 1], e2 = b[j + 2], e3 = b[j + 3];
        a0 += e0.y * weight[(long long)__float_as_int(e0.x) * FEAT + f];
        a1 += e1.y * weight[(long long)__float_as_int(e1.x) * FEAT + f];
        a2 += e2.y * weight[(long long)__float_as_int(e2.x) * FEAT + f];
        a3 += e3.y * weight[(long long)__float_as_int(e3.x) * FEAT + f];
    }
    for (; j < n; ++j) {
        float2 e0 = b[j];
        a0 += e0.y * weight[(long long)__float_as_int(e0.x) * FEAT + f];
    }
    out[(long long)g * FEAT + f] += (a0 + a1) + (a2 + a3);
}

// ---------------- v0 fallback ----------------

__global__ __launch_bounds__(256) void gnn_init_out(
    const float* __restrict__ bias, float* __restrict__ out, int total) {
    int i = blockIdx.x * blockDim.x + threadIdx.x;
    if (i < total) out[i] = bias[i & (FEAT - 1)];
}

__global__ __launch_bounds__(256) void gnn_scatter(
    const int* __restrict__ edge_row,
    const int* __restrict__ edge_col,
    const float* __restrict__ edge_val,
    const float* __restrict__ weight,
    float* __restrict__ out,
    int num_edges) {
    long long t = (long long)blockIdx.x * blockDim.x + threadIdx.x;
    int e = (int)(t >> 5);
    int f = (int)(t & (FEAT - 1));
    if (e < num_edges) {
        int r = edge_row[e];
        int c = edge_col[e];
        atomicAdd(out + r * FEAT + f, edge_val[e] * weight[c * FEAT + f]);
    }
}

extern "C" void kernel_launch(void* const* d_in, const int* in_sizes, int n_in,
                              void* d_out, int out_size, void* d_ws, size_t ws_size,
                              hipStream_t stream) {
    const int*   edge_row = (const int*)d_in[0];
    const int*   edge_col = (const int*)d_in[1];
    const float* edge_val = (const float*)d_in[2];
    const float* weight   = (const float*)d_in[3];
    const float* bias     = (const float*)d_in[4];
    float* out = (float*)d_out;

    const int E = in_sizes[0];
    const int total = out_size;        // N * 32 elements
    const int N = total / FEAT;
    const int B = (N + RPB - 1) >> LOG_RPB;

    auto align256 = [](size_t x) { return (x + 255) & ~(size_t)255; };
    size_t cursor_off = 0;
    size_t scnt_off   = align256(cursor_off + (size_t)B * sizeof(int));
    size_t spill_off  = align256(scnt_off + sizeof(int));
    size_t parts_off  = align256(spill_off + (size_t)E * sizeof(float4));
    size_t need_v7    = parts_off + (size_t)B * CAPB * sizeof(float2);

    if (B >= 1 && B <= BMAX && N <= (1 << COLBITS) && E > 0 && ws_size >= need_v7) {
        int*    cursor = (int*)((char*)d_ws + cursor_off);
        int*    scnt   = (int*)((char*)d_ws + scnt_off);
        float4* spill  = (float4*)((char*)d_ws + spill_off);
        float2* parts  = (float2*)((char*)d_ws + parts_off);

        gnn_zero<<<(B + 1 + 255) / 256, 256, 0, stream>>>(cursor, scnt, B);
        gnn_part<<<(E + PCHUNK - 1) / PCHUNK, PTHREADS, 0, stream>>>(
            edge_row, edge_col, edge_val, cursor, parts, spill, scnt, E, B);
        gnn_accum<<<B, 512, 0, stream>>>(
            parts, cursor, scnt, spill, weight, bias, out, N);
        return;
    }

    // v2 fallback: bin + gather
    size_t cnt_bytes = align256((size_t)N * sizeof(int));
    long long cap_ll = 0;
    if (ws_size > cnt_bytes)
        cap_ll = (long long)((ws_size - cnt_bytes) / ((size_t)N * sizeof(float2)));
    int cap = (int)(cap_ll > CAP_MAX ? CAP_MAX : cap_ll);

    if (cap >= 16) {
        int* cnt = (int*)d_ws;
        float2* bins = (float2*)((char*)d_ws + cnt_bytes);
        int total4 = total / 4;
        int init_threads = total4 > N ? total4 : N;
        gnn_init<<<(init_threads + 255) / 256, 256, 0, stream>>>(
            bias, out, cnt, total4, N);
        gnn_bin<<<(E + 255) / 256, 256, 0, stream>>>(
            edge_row, edge_col, edge_val, weight, bins, cnt, out, E, cap);
        long long gthreads = (long long)N * FEAT;
        gnn_gather<<<(int)((gthreads + 255) / 256), 256, 0, stream>>>(
            bins, cnt, weight, out, N, cap);
    } else {
        gnn_init_out<<<(total + 255) / 256, 256, 0, stream>>>(bias, out, total);
        long long threads = (long long)E * FEAT;
        gnn_scatter<<<(int)((threads + 255) / 256), 256, 0, stream>>>(
            edge_row, edge_col, edge_val, weight, out, E);
    }
}

// Round 8
// 122.132 us; speedup vs baseline: 4.0182x; 1.0280x over previous
//
#include <hip/hip_runtime.h>

// out[N,32] = segment_sum(edge_val[e] * weight[edge_col[e], :], edge_row[e]) + bias
//
// v8: v7 structure with the accum gather restructured for 4x memory-level
// parallelism per load instruction:
//   - accum: 8-LANE groups, float4 weight loads. One global_load_dwordx4 wave
//     instruction now fetches 8 records' weight lines (vs 2 with 32-lane
//     groups + dword loads); 8-deep unroll -> 64 lines in flight per wave.
//     Each group owns 2 rows, float4 accumulator, 128B coalesced row store.
//   - part: 1024-wide Hillis-Steele scan (20 barriers) -> two-level __shfl_up
//     wave scan (3 barriers).
//   K0 gnn_zero : cursor[B]=0, scnt=0
//   K1 gnn_part : per 4096-edge chunk: vector edge loads, fused hist+slot,
//                 wave scan, global run reservation, LDS bucket-order scatter
//                 (no atomics), coalesced writeout; overflow -> exact spill.
//   K2 gnn_accum: per bucket (512 thr): regs load, fused row hist+slot, wave
//                 scan, LDS row-sort scatter (no atomics), 64 groups x 8 lanes
//                 register-gather w/ float4, spill merge, coalesced store+bias.
//
// Fallbacks: v2 bin+gather if ws too small / shape out of range; v0 atomics last.

#define FEAT 32
#define LOG_RPB 7
#define RPB (1 << LOG_RPB)
#define COLBITS 17
#define CMASK ((1u << COLBITS) - 1)
#define BMAX 1024
#define PCHUNK 4096
#define PTHREADS 1024
#define EPT (PCHUNK / PTHREADS)      // 4 edges per thread
#define CAPB 2560                    // record slots per bucket (mult of 512)
#define CAP_MAX 32

// ---------------- v8 kernels ----------------

__global__ __launch_bounds__(256) void gnn_zero(
    int* __restrict__ cursor, int* __restrict__ scnt, int B) {
    int i = blockIdx.x * 256 + threadIdx.x;
    if (i < B) cursor[i] = 0;
    if (i == B) *scnt = 0;
}

__global__ __launch_bounds__(PTHREADS) void gnn_part(
    const int* __restrict__ edge_row,
    const int* __restrict__ edge_col,
    const float* __restrict__ edge_val,
    int* __restrict__ cursor,
    float2* __restrict__ parts,
    float4* __restrict__ spill,
    int* __restrict__ scnt,
    int num_edges, int B) {
    __shared__ float2 lrec[PCHUNK];              // 32 KB
    __shared__ unsigned short lbkt[PCHUNK];      // 8 KB
    __shared__ int hcur[BMAX];                   // hist+slots, then run base
    __shared__ int st[BMAX];                     // exclusive starts
    __shared__ int wtot[16], wbase[16];
    int t = threadIdx.x;
    hcur[t] = 0;
    __syncthreads();

    int e0 = blockIdx.x * PCHUNK;
    int cnt_chunk = num_edges - e0;
    if (cnt_chunk > PCHUNK) cnt_chunk = PCHUNK;

    // 1) vectorized edge loads + fused histogram/slot assignment
    int  r[EPT], c[EPT], bb[EPT], slot[EPT];
    float vv[EPT];
    int ebase = e0 + 4 * t;
    if (ebase + 3 < num_edges) {
        int4  r4 = *(const int4*)(edge_row + ebase);
        int4  c4 = *(const int4*)(edge_col + ebase);
        float4 v4 = *(const float4*)(edge_val + ebase);
        r[0] = r4.x; r[1] = r4.y; r[2] = r4.z; r[3] = r4.w;
        c[0] = c4.x; c[1] = c4.y; c[2] = c4.z; c[3] = c4.w;
        vv[0] = v4.x; vv[1] = v4.y; vv[2] = v4.z; vv[3] = v4.w;
    } else {
        #pragma unroll
        for (int k = 0; k < EPT; ++k) {
            int e = ebase + k;
            bool ok = e < num_edges;
            r[k]  = ok ? edge_row[e] : -1;
            c[k]  = ok ? edge_col[e] : 0;
            vv[k] = ok ? edge_val[e] : 0.f;
        }
    }
    #pragma unroll
    for (int k = 0; k < EPT; ++k) {
        if (r[k] >= 0) {
            bb[k] = r[k] >> LOG_RPB;
            slot[k] = atomicAdd(&hcur[bb[k]], 1);   // rank within bucket
        }
    }
    __syncthreads();

    // 2) two-level shfl scan of counts (3 barriers) + global run reservation
    int v = hcur[t];
    int wid = t >> 6, lane = t & 63;
    int x = v;
    #pragma unroll
    for (int off = 1; off < 64; off <<= 1) {
        int y = __shfl_up(x, off);
        if (lane >= off) x += y;
    }
    if (lane == 63) wtot[wid] = x;
    __syncthreads();
    if (t < 16) {
        int w = wtot[t], xx = w;
        #pragma unroll
        for (int off = 1; off < 16; off <<= 1) {
            int y = __shfl_up(xx, off);
            if (t >= off) xx += y;
        }
        wbase[t] = xx - w;
    }
    __syncthreads();
    int ex = x - v + wbase[wid];                 // exclusive start
    st[t] = ex;
    int rbase = 0;
    if (t < B && v) rbase = atomicAdd(&cursor[t], v);
    hcur[t] = rbase;                             // reuse as global run base
    __syncthreads();

    // 3) scatter into LDS in bucket order — NO atomics (slot known)
    #pragma unroll
    for (int k = 0; k < EPT; ++k) {
        if (r[k] >= 0) {
            int pos = st[bb[k]] + slot[k];
            unsigned pk = (unsigned)c[k] |
                          ((unsigned)(r[k] & (RPB - 1)) << COLBITS);
            lrec[pos] = make_float2(__uint_as_float(pk), vv[k]);
            lbkt[pos] = (unsigned short)bb[k];
        }
    }
    __syncthreads();

    // 4) coalesced writeout (consecutive i -> consecutive slots of one bucket)
    for (int i = t; i < cnt_chunk; i += PTHREADS) {
        int b2 = lbkt[i];
        float2 rec = lrec[i];
        int s = hcur[b2] + (i - st[b2]);
        if (s < CAPB) {
            parts[(long long)b2 * CAPB + s] = rec;
        } else {
            // exact overflow path (never taken for uniform data)
            int si = atomicAdd(scnt, 1);
            unsigned pk = __float_as_uint(rec.x);
            spill[si] = make_float4(
                __uint_as_float((unsigned)(b2 << LOG_RPB) + (pk >> COLBITS)),
                __uint_as_float(pk & CMASK), rec.y, 0.f);
        }
    }
}

__global__ __launch_bounds__(512) void gnn_accum(
    const float2* __restrict__ parts,
    const int* __restrict__ cursor,
    const int* __restrict__ scnt,
    const float4* __restrict__ spill,
    const float* __restrict__ weight,
    const float* __restrict__ bias,
    float* __restrict__ out,
    int n_nodes) {
    __shared__ float2 srec[CAPB];       // 20 KB: row-sorted records
    __shared__ int h[RPB];
    __shared__ int rs[RPB + 1];
    int b = blockIdx.x, t = threadIdx.x;
    int n = cursor[b];
    int nspill = *scnt;                 // uniform; 0 in the common case
    int m = n < CAPB ? n : CAPB;
    const float2* p = parts + (long long)b * CAPB;

    // 1) load records to registers + fused row histogram/slot
    float2 rec[CAPB / 512];
    int rl[CAPB / 512], slot[CAPB / 512];
    if (t < RPB) h[t] = 0;
    __syncthreads();
    #pragma unroll
    for (int k = 0; k < CAPB / 512; ++k) {
        int idx = t + k * 512;
        bool ok = idx < m;
        rec[k] = ok ? p[idx] : make_float2(0.f, 0.f);
        if (ok) {
            rl[k] = (int)((__float_as_uint(rec[k].x) >> COLBITS) & (RPB - 1));
            slot[k] = atomicAdd(&h[rl[k]], 1);     // rank within row
        }
    }
    __syncthreads();

    // 2) wave-0 scan of 128 row counts via shfl (2 elems/lane)
    if (t < 64) {
        int a  = h[2 * t];
        int c2 = h[2 * t + 1];
        int pr = a + c2;
        int x = pr;
        #pragma unroll
        for (int off = 1; off < 64; off <<= 1) {
            int y = __shfl_up(x, off);
            if (t >= off) x += y;
        }
        int exc = x - pr;
        rs[2 * t] = exc;
        rs[2 * t + 1] = exc + a;
        if (t == 63) rs[RPB] = x;
    }
    __syncthreads();

    // 3) scatter registers -> row-sorted LDS — NO atomics
    #pragma unroll
    for (int k = 0; k < CAPB / 512; ++k) {
        int idx = t + k * 512;
        if (idx < m) srec[rs[rl[k]] + slot[k]] = rec[k];
    }
    __syncthreads();

    // 4) register-accumulate gather: 64 groups of 8 lanes; group owns 2 rows.
    //    Lane l loads weight[col][4l..4l+3] (float4): one wave load instruction
    //    fetches 8 records' 128B lines; 8-deep unroll -> 64 lines in flight.
    int g = t >> 3;                     // 64 groups
    int l = t & 7;
    int row0 = b << LOG_RPB;
    float4 bf4 = ((const float4*)bias)[l];
    #pragma unroll 1
    for (int rr = 0; rr < 2; ++rr) {
        int rlc = (g << 1) + rr;
        int s = rs[rlc], e = rs[rlc + 1];
        float4 acc = make_float4(0.f, 0.f, 0.f, 0.f);
        for (int j = s; j < e; j += 8) {
            unsigned pk[8]; float vv[8];
            #pragma unroll
            for (int k = 0; k < 8; ++k) {
                int jj = j + k;
                float2 rc = srec[jj < e ? jj : s];      // broadcast LDS read
                pk[k] = __float_as_uint(rc.x);
                vv[k] = rc.y;
            }
            float4 w4[8];
            #pragma unroll
            for (int k = 0; k < 8; ++k)
                w4[k] = *(const float4*)(
                    weight + (long long)(pk[k] & CMASK) * FEAT + (l << 2));
            #pragma unroll
            for (int k = 0; k < 8; ++k) {
                float sc = (j + k < e) ? vv[k] : 0.f;
                acc.x += sc * w4[k].x;
                acc.y += sc * w4[k].y;
                acc.z += sc * w4[k].z;
                acc.w += sc * w4[k].w;
            }
        }
        // merge rare spill entries for this row (nspill==0 normally)
        if (nspill > 0) {
            for (int i = 0; i < nspill; ++i) {
                float4 sp = spill[i];
                if ((int)__float_as_uint(sp.x) == row0 + rlc) {
                    float4 wz = *(const float4*)(
                        weight + (long long)__float_as_uint(sp.y) * FEAT +
                        (l << 2));
                    acc.x += sp.z * wz.x;
                    acc.y += sp.z * wz.y;
                    acc.z += sp.z * wz.z;
                    acc.w += sp.z * wz.w;
                }
            }
        }
        int rrow = row0 + rlc;
        if (rrow < n_nodes) {
            float4 o = make_float4(acc.x + bf4.x, acc.y + bf4.y,
                                   acc.z + bf4.z, acc.w + bf4.w);
            *(float4*)(out + (long long)rrow * FEAT + (l << 2)) = o;
        }
    }
}

// ---------------- v2 fallback (bin + gather) ----------------

__global__ __launch_bounds__(256) void gnn_init(
    const float* __restrict__ bias, float* __restrict__ out,
    int* __restrict__ cnt, int total4, int n_nodes) {
    int i = blockIdx.x * blockDim.x + threadIdx.x;
    if (i < total4) {
        float4 bb = ((const float4*)bias)[i & 7];
        ((float4*)out)[i] = bb;
    }
    if (i < n_nodes) cnt[i] = 0;
}

__global__ __launch_bounds__(256) void gnn_bin(
    const int* __restrict__ edge_row,
    const int* __restrict__ edge_col,
    const float* __restrict__ edge_val,
    const float* __restrict__ weight,
    float2* __restrict__ bins,
    int* __restrict__ cnt,
    float* __restrict__ out,
    int num_edges, int cap) {
    int e = blockIdx.x * blockDim.x + threadIdx.x;
    if (e >= num_edges) return;
    int r = edge_row[e];
    int c = edge_col[e];
    float v = edge_val[e];
    int slot = atomicAdd(&cnt[r], 1);
    if (slot < cap) {
        bins[(long long)r * cap + slot] = make_float2(__int_as_float(c), v);
    } else {
        const float* w = weight + (long long)c * FEAT;
        #pragma unroll
        for (int f = 0; f < FEAT; ++f)
            atomicAdd(out + (long long)r * FEAT + f, v * w[f]);
    }
}

__global__ __launch_bounds__(256) void gnn_gather(
    const float2* __restrict__ bins,
    const int* __restrict__ cnt,
    const float* __restrict__ weight,
    float* __restrict__ out,
    int n_nodes, int cap) {
    int g = (blockIdx.x * blockDim.x + threadIdx.x) >> 5;
    int f = threadIdx.x & (FEAT - 1);
    if (g >= n_nodes) return;
    int n = cnt[g];
    n = n < cap ? n : cap;
    const float2* b = bins + (long long)g * cap;
    float a0 = 0.f, a1 = 0.f, a2 = 0.f, a3 = 0.f;
    int j = 0;
    for (; j + 4 <= n; j += 4) {
        float2 e0 = b[j], e1 = b[j + 1], e2 = b[j + 2], e3 = b[j + 3];
        a0 += e0.y * weight[(long long)__float_as_int(e0.x) * FEAT + f];
        a1 += e1.y * weight[(long long)__float_as_int(e1.x) * FEAT + f];
        a2 += e2.y * weight[(long long)__float_as_int(e2.x) * FEAT + f];
        a3 += e3.y * weight[(long long)__float_as_int(e3.x) * FEAT + f];
    }
    for (; j < n; ++j) {
        float2 e0 = b[j];
        a0 += e0.y * weight[(long long)__float_as_int(e0.x) * FEAT + f];
    }
    out[(long long)g * FEAT + f] += (a0 + a1) + (a2 + a3);
}

// ---------------- v0 fallback ----------------

__global__ __launch_bounds__(256) void gnn_init_out(
    const float* __restrict__ bias, float* __restrict__ out, int total) {
    int i = blockIdx.x * blockDim.x + threadIdx.x;
    if (i < total) out[i] = bias[i & (FEAT - 1)];
}

__global__ __launch_bounds__(256) void gnn_scatter(
    const int* __restrict__ edge_row,
    const int* __restrict__ edge_col,
    const float* __restrict__ edge_val,
    const float* __restrict__ weight,
    float* __restrict__ out,
    int num_edges) {
    long long t = (long long)blockIdx.x * blockDim.x + threadIdx.x;
    int e = (int)(t >> 5);
    int f = (int)(t & (FEAT - 1));
    if (e < num_edges) {
        int r = edge_row[e];
        int c = edge_col[e];
        atomicAdd(out + r * FEAT + f, edge_val[e] * weight[c * FEAT + f]);
    }
}

extern "C" void kernel_launch(void* const* d_in, const int* in_sizes, int n_in,
                              void* d_out, int out_size, void* d_ws, size_t ws_size,
                              hipStream_t stream) {
    const int*   edge_row = (const int*)d_in[0];
    const int*   edge_col = (const int*)d_in[1];
    const float* edge_val = (const float*)d_in[2];
    const float* weight   = (const float*)d_in[3];
    const float* bias     = (const float*)d_in[4];
    float* out = (float*)d_out;

    const int E = in_sizes[0];
    const int total = out_size;        // N * 32 elements
    const int N = total / FEAT;
    const int B = (N + RPB - 1) >> LOG_RPB;

    auto align256 = [](size_t x) { return (x + 255) & ~(size_t)255; };
    size_t cursor_off = 0;
    size_t scnt_off   = align256(cursor_off + (size_t)B * sizeof(int));
    size_t spill_off  = align256(scnt_off + sizeof(int));
    size_t parts_off  = align256(spill_off + (size_t)E * sizeof(float4));
    size_t need_v8    = parts_off + (size_t)B * CAPB * sizeof(float2);

    if (B >= 1 && B <= BMAX && N <= (1 << COLBITS) && E > 0 && ws_size >= need_v8) {
        int*    cursor = (int*)((char*)d_ws + cursor_off);
        int*    scnt   = (int*)((char*)d_ws + scnt_off);
        float4* spill  = (float4*)((char*)d_ws + spill_off);
        float2* parts  = (float2*)((char*)d_ws + parts_off);

        gnn_zero<<<(B + 1 + 255) / 256, 256, 0, stream>>>(cursor, scnt, B);
        gnn_part<<<(E + PCHUNK - 1) / PCHUNK, PTHREADS, 0, stream>>>(
            edge_row, edge_col, edge_val, cursor, parts, spill, scnt, E, B);
        gnn_accum<<<B, 512, 0, stream>>>(
            parts, cursor, scnt, spill, weight, bias, out, N);
        return;
    }

    // v2 fallback: bin + gather
    size_t cnt_bytes = align256((size_t)N * sizeof(int));
    long long cap_ll = 0;
    if (ws_size > cnt_bytes)
        cap_ll = (long long)((ws_size - cnt_bytes) / ((size_t)N * sizeof(float2)));
    int cap = (int)(cap_ll > CAP_MAX ? CAP_MAX : cap_ll);

    if (cap >= 16) {
        int* cnt = (int*)d_ws;
        float2* bins = (float2*)((char*)d_ws + cnt_bytes);
        int total4 = total / 4;
        int init_threads = total4 > N ? total4 : N;
        gnn_init<<<(init_threads + 255) / 256, 256, 0, stream>>>(
            bias, out, cnt, total4, N);
        gnn_bin<<<(E + 255) / 256, 256, 0, stream>>>(
            edge_row, edge_col, edge_val, weight, bins, cnt, out, E, cap);
        long long gthreads = (long long)N * FEAT;
        gnn_gather<<<(int)((gthreads + 255) / 256), 256, 0, stream>>>(
            bins, cnt, weight, out, N, cap);
    } else {
        gnn_init_out<<<(total + 255) / 256, 256, 0, stream>>>(bias, out, total);
        long long threads = (long long)E * FEAT;
        gnn_scatter<<<(int)((threads + 255) / 256), 256, 0, stream>>>(
            edge_row, edge_col, edge_val, weight, out, E);
    }
}